// Round 2
// baseline (11612.676 us; speedup 1.0000x reference)
//
#include <hip/hip_runtime.h>

typedef _Float16 f16;
typedef __attribute__((ext_vector_type(8))) _Float16 f16x8;
typedef __attribute__((ext_vector_type(4))) float f32x4;

#define HID 512
#define DIMS_X 16
#define NSTEPS 127
#define BM 64
#define BATCH 32768

// ws f16 layout offsets (elements)
#define OFF_W0 0
#define OFF_W1 32768
#define OFF_W2 (32768 + 262144)
#define OFF_W3 (32768 + 2 * 262144)
#define OFF_W4 (32768 + 3 * 262144)

// Pack f32 row-major [K][N] weights into f16 fragment-linear [Kpad/8][N][8],
// zero-padding rows K..Kpad-1.
__global__ void pack_w_kernel(const float* __restrict__ w, f16* __restrict__ out,
                              int K, int Kpad, int N) {
    int idx = blockIdx.x * blockDim.x + threadIdx.x;
    if (idx >= Kpad * N) return;
    int k = idx / N, n = idx - k * N;
    float v = (k < K) ? w[k * N + n] : 0.0f;
    out[(((k >> 3) * N) + n) * 8 + (k & 7)] = (f16)v;
}

__device__ __forceinline__ unsigned rotl32(unsigned x, int r) {
    return (x << r) | (x >> (32 - r));
}

// Threefry-2x32-20, matching jax._src.prng.threefry2x32 exactly.
__device__ __forceinline__ void threefry2x32(unsigned k0, unsigned k1,
                                             unsigned c0, unsigned c1,
                                             unsigned& o0, unsigned& o1) {
    unsigned ks2 = k0 ^ k1 ^ 0x1BD11BDAu;
    unsigned x0 = c0 + k0, x1 = c1 + k1;
#define TF_R(rot) { x0 += x1; x1 = rotl32(x1, rot); x1 ^= x0; }
    TF_R(13) TF_R(15) TF_R(26) TF_R(6)
    x0 += k1;  x1 += ks2 + 1u;
    TF_R(17) TF_R(29) TF_R(16) TF_R(24)
    x0 += ks2; x1 += k0 + 2u;
    TF_R(13) TF_R(15) TF_R(26) TF_R(6)
    x0 += k0;  x1 += k1 + 3u;
    TF_R(17) TF_R(29) TF_R(16) TF_R(24)
    x0 += k1;  x1 += ks2 + 4u;
    TF_R(13) TF_R(15) TF_R(26) TF_R(6)
    x0 += ks2; x1 += k0 + 5u;
#undef TF_R
    o0 = x0; o1 = x1;
}

// XLA's f32 ErfInv expansion (Giles polynomial) — same coefficients as
// chlo.erf_inv lowering, so we track the JAX reference to ~1 ulp.
__device__ __forceinline__ float erfinv_xla(float x) {
    float w = -log1pf(-x * x);
    float p;
    if (w < 5.0f) {
        w = w - 2.5f;
        p = 2.81022636e-08f;
        p = fmaf(p, w, 3.43273939e-07f);
        p = fmaf(p, w, -3.5233877e-06f);
        p = fmaf(p, w, -4.39150654e-06f);
        p = fmaf(p, w, 0.00021858087f);
        p = fmaf(p, w, -0.00125372503f);
        p = fmaf(p, w, -0.00417768164f);
        p = fmaf(p, w, 0.246640727f);
        p = fmaf(p, w, 1.50140941f);
    } else {
        w = sqrtf(w) - 3.0f;
        p = -0.000200214257f;
        p = fmaf(p, w, 0.000100950558f);
        p = fmaf(p, w, 0.00134934322f);
        p = fmaf(p, w, -0.00367342844f);
        p = fmaf(p, w, 0.00573950773f);
        p = fmaf(p, w, -0.0076224613f);
        p = fmaf(p, w, 0.00943887047f);
        p = fmaf(p, w, 1.00167406f);
        p = fmaf(p, w, 2.83297682f);
    }
    return p * x;
}

// LDS byte offset with XOR swizzle: element (row, col) of a [64][512] f16 tile
// lives at row*1024 + ((col*2) ^ ((row&7)<<4)). Keeps ds_read_b128 2-way max.
__device__ __forceinline__ unsigned lds_off(int row, int colByte) {
    return (unsigned)(row * 1024 + (colByte ^ ((row & 7) << 4)));
}

template <int NKC>
__device__ __forceinline__ void run_layer(const f16* src, f16* dst,
                                          const f16* __restrict__ Wp,
                                          const float* bias,
                                          int wv, int lk, int lc) {
    f32x4 acc[4][4];
#pragma unroll
    for (int a = 0; a < 4; ++a)
#pragma unroll
        for (int b = 0; b < 4; ++b)
            acc[a][b] = (f32x4){0.f, 0.f, 0.f, 0.f};

    const int colbase = wv * 64;
#pragma unroll 2
    for (int kc = 0; kc < NKC; ++kc) {
        f16x8 afr[4];
#pragma unroll
        for (int tr = 0; tr < 4; ++tr) {
            int row = tr * 16 + lc;  // A frag: row = lane&15, k = (lane>>4)*8+e
            afr[tr] = *(const f16x8*)((const char*)src + lds_off(row, kc * 64 + lk * 16));
        }
#pragma unroll
        for (int tc = 0; tc < 4; ++tc) {
            f16x8 bfr = *(const f16x8*)(Wp + ((size_t)(kc * 4 + lk) * HID + colbase + tc * 16 + lc) * 8);
#pragma unroll
            for (int tr = 0; tr < 4; ++tr)
                acc[tr][tc] = __builtin_amdgcn_mfma_f32_16x16x32_f16(afr[tr], bfr, acc[tr][tc], 0, 0, 0);
        }
    }
    // epilogue: relu(acc + bias) -> f16 -> dst. D frag: col=lane&15, row=(lane>>4)*4+r
#pragma unroll
    for (int tr = 0; tr < 4; ++tr)
#pragma unroll
        for (int tc = 0; tc < 4; ++tc)
#pragma unroll
            for (int r = 0; r < 4; ++r) {
                float v = acc[tr][tc][r] + bias[tc];
                v = fmaxf(v, 0.0f);
                int row = tr * 16 + lk * 4 + r;
                int cb = (colbase + tc * 16 + lc) * 2;
                *(f16*)((char*)dst + lds_off(row, cb)) = (f16)v;
            }
}

__global__ __launch_bounds__(512, 2) void didi_main(
    const float* __restrict__ x1g,
    const float* __restrict__ b0g, const float* __restrict__ b1g,
    const float* __restrict__ b2g, const float* __restrict__ b3g,
    const float* __restrict__ b4g,
    const f16* __restrict__ wsp,
    float* __restrict__ outg) {
    __shared__ __align__(16) f16 bufA[BM * HID];
    __shared__ __align__(16) f16 bufB[BM * HID];

    const f16* W0p = wsp + OFF_W0;
    const f16* W1p = wsp + OFF_W1;
    const f16* W2p = wsp + OFF_W2;
    const f16* W3p = wsp + OFF_W3;
    const f16* W4p = wsp + OFF_W4;

    const int tid = threadIdx.x;
    const int wv = tid >> 6;   // wave 0..7
    const int ln = tid & 63;
    const int lk = ln >> 4;    // k-group 0..3
    const int lc = ln & 15;    // 0..15
    const int rowBase = blockIdx.x * BM;

    // Per-layer bias fragments for this wave's 64 output columns (constant over steps).
    float bias0[4], bias1[4], bias2[4], bias3[4];
#pragma unroll
    for (int tc = 0; tc < 4; ++tc) {
        int col = wv * 64 + tc * 16 + lc;
        bias0[tc] = b0g[col];
        bias1[tc] = b1g[col];
        bias2[tc] = b2g[col];
        bias3[tc] = b3g[col];
    }
    float bias4 = b4g[lc];

    // Zero bufA so untouched cols (33..63) are 0 (avoids NaN*0 in the padded K of L0).
    {
        f16x8 z = {};
        for (int o = tid; o < (BM * HID) / 8; o += 512)
            *(f16x8*)(bufA + o * 8) = z;
    }
    __syncthreads();

    // x state lives in registers of waves 0..3 (D-fragment layout: 4 rows x 1 col per lane).
    float xreg[4], x1reg[4];
    if (wv < 4) {
#pragma unroll
        for (int r = 0; r < 4; ++r) {
            int lrow = wv * 16 + lk * 4 + r;
            float v = x1g[(rowBase + lrow) * DIMS_X + lc];
            x1reg[r] = v;
            xreg[r] = v;  // x0 = x_1
            *(f16*)((char*)bufA + lds_off(lrow, (1 + lc) * 2)) = (f16)v;   // x_t cols 1..16
            *(f16*)((char*)bufA + lds_off(lrow, (17 + lc) * 2)) = (f16)v;  // x_1 cols 17..32
            if (lc == 0)
                *(f16*)((char*)bufA + lds_off(lrow, 0)) = (f16)1.0f;       // t col, t0 = 1
        }
    }
    __syncthreads();

    const float dstep = -1.0f / 127.0f;

#pragma unroll 1
    for (int i = 0; i < NSTEPS; ++i) {
        run_layer<2>(bufA, bufB, W0p, bias0, wv, lk, lc);
        __syncthreads();
        run_layer<16>(bufB, bufA, W1p, bias1, wv, lk, lc);
        __syncthreads();
        run_layer<16>(bufA, bufB, W2p, bias2, wv, lk, lc);
        __syncthreads();
        run_layer<16>(bufB, bufA, W3p, bias3, wv, lk, lc);
        __syncthreads();

        float t  = 1.0f + (float)i * dstep;
        float tp = (i == NSTEPS - 1) ? 0.0f : 1.0f + (float)(i + 1) * dstep;

        if (wv < 4) {
            // Layer 4: this wave's 16 rows x 16 cols, K=512.
            f32x4 acc = {0.f, 0.f, 0.f, 0.f};
#pragma unroll 4
            for (int kc = 0; kc < 16; ++kc) {
                int row = wv * 16 + lc;
                f16x8 a = *(const f16x8*)((const char*)bufA + lds_off(row, kc * 64 + lk * 16));
                f16x8 b = *(const f16x8*)(W4p + ((size_t)(kc * 4 + lk) * 16 + lc) * 8);
                acc = __builtin_amdgcn_mfma_f32_16x16x32_f16(a, b, acc, 0, 0, 0);
            }
            float ca = (t - tp) / t;
            float cb = tp / t;
            float sig = sqrtf(((0.01f * tp) * (t - tp)) / t);
            unsigned fk0, fk1;
            threefry2x32(0u, 42u, 0u, (unsigned)i, fk0, fk1);  // fold_in(key(42), i)
#pragma unroll
            for (int r = 0; r < 4; ++r) {
                float drift = acc[r] + bias4;
                int lrow = wv * 16 + lk * 4 + r;
                unsigned flat = (unsigned)(rowBase + lrow) * 16u + (unsigned)lc;
                // jax_threefry_partitionable=True (modern JAX default):
                // 64-bit counter = flat index -> (c0,c1) = (0, flat); 32-bit draw = o0 ^ o1.
                unsigned o0, o1;
                threefry2x32(fk0, fk1, 0u, flat, o0, o1);
                unsigned bits = o0 ^ o1;
                // jax uniform(minval=nextafter(-1,0), maxval=1): scale folds to exactly 2.0f
                float u01 = __uint_as_float((bits >> 9) | 0x3f800000u) - 1.0f;
                float u = u01 * 2.0f + (-0.99999994f);
                u = fmaxf(-0.99999994f, u);
                float nz = 1.4142135623730951f * erfinv_xla(u);
                float x = xreg[r];
                float pred = x - t * drift;
                float xn = ca * pred + cb * x;
                xn = xn + sig * nz;
                xreg[r] = xn;
                // stage next step's input (own rows only -> no cross-wave hazard)
                *(f16*)((char*)bufA + lds_off(lrow, (1 + lc) * 2)) = (f16)xn;
                *(f16*)((char*)bufA + lds_off(lrow, (17 + lc) * 2)) = (f16)x1reg[r];
                if (lc == 0)
                    *(f16*)((char*)bufA + lds_off(lrow, 0)) = (f16)tp;
            }
        }
        __syncthreads();
    }

    if (wv < 4) {
#pragma unroll
        for (int r = 0; r < 4; ++r) {
            int grow = rowBase + wv * 16 + lk * 4 + r;
            outg[grow * 16 + lc] = xreg[r];
        }
    }
}

extern "C" void kernel_launch(void* const* d_in, const int* in_sizes, int n_in,
                              void* d_out, int out_size, void* d_ws, size_t ws_size,
                              hipStream_t stream) {
    const float* x1 = (const float*)d_in[0];
    const float* w0 = (const float*)d_in[1];
    const float* b0 = (const float*)d_in[2];
    const float* w1 = (const float*)d_in[3];
    const float* b1 = (const float*)d_in[4];
    const float* w2 = (const float*)d_in[5];
    const float* b2 = (const float*)d_in[6];
    const float* w3 = (const float*)d_in[7];
    const float* b3 = (const float*)d_in[8];
    const float* w4 = (const float*)d_in[9];
    const float* b4 = (const float*)d_in[10];
    f16* ws = (f16*)d_ws;

    hipLaunchKernelGGL(pack_w_kernel, dim3(128), dim3(256), 0, stream, w0, ws + OFF_W0, 33, 64, 512);
    hipLaunchKernelGGL(pack_w_kernel, dim3(1024), dim3(256), 0, stream, w1, ws + OFF_W1, 512, 512, 512);
    hipLaunchKernelGGL(pack_w_kernel, dim3(1024), dim3(256), 0, stream, w2, ws + OFF_W2, 512, 512, 512);
    hipLaunchKernelGGL(pack_w_kernel, dim3(1024), dim3(256), 0, stream, w3, ws + OFF_W3, 512, 512, 512);
    hipLaunchKernelGGL(pack_w_kernel, dim3(32), dim3(256), 0, stream, w4, ws + OFF_W4, 512, 512, 16);

    hipLaunchKernelGGL(didi_main, dim3(BATCH / BM), dim3(512), 0, stream,
                       x1, b0, b1, b2, b3, b4, (const f16*)ws, (float*)d_out);
}

// Round 3
// 8994.939 us; speedup vs baseline: 1.2910x; 1.2910x over previous
//
#include <hip/hip_runtime.h>

typedef _Float16 f16;
typedef __attribute__((ext_vector_type(4))) _Float16 f16x4;
typedef __attribute__((ext_vector_type(8))) _Float16 f16x8;
typedef __attribute__((ext_vector_type(4))) float f32x4;

#define HID 512
#define DIMS_X 16
#define NSTEPS 127
#define BM 64
#define BATCH 32768

// ws f16 layout offsets (elements)
#define OFF_W0 0
#define OFF_W1 32768
#define OFF_W2 (32768 + 262144)
#define OFF_W3 (32768 + 2 * 262144)
#define OFF_W4 (32768 + 3 * 262144)

// Pack f32 row-major [K][N] weights into f16 fragment-linear [Kpad/8][N][8].
__global__ void pack_w_kernel(const float* __restrict__ w, f16* __restrict__ out,
                              int K, int Kpad, int N) {
    int idx = blockIdx.x * blockDim.x + threadIdx.x;
    if (idx >= Kpad * N) return;
    int k = idx / N, n = idx - k * N;
    float v = (k < K) ? w[k * N + n] : 0.0f;
    out[(((k >> 3) * N) + n) * 8 + (k & 7)] = (f16)v;
}

// W0 pack with input-row permutation to the kernel's input layout:
// new rows 0-15 = x_t (orig rows 1..16), 16-31 = x_1 (orig 17..32), 32 = t (orig 0), 33-63 = 0.
__global__ void pack_w0_kernel(const float* __restrict__ w, f16* __restrict__ out) {
    int idx = blockIdx.x * blockDim.x + threadIdx.x;
    if (idx >= 64 * HID) return;
    int kn = idx / HID, n = idx - kn * HID;
    float v;
    if (kn < 32) v = w[(kn + 1) * HID + n];
    else if (kn == 32) v = w[n];
    else v = 0.0f;
    out[(((kn >> 3) * HID) + n) * 8 + (kn & 7)] = (f16)v;
}

__device__ __forceinline__ unsigned rotl32(unsigned x, int r) {
    return (x << r) | (x >> (32 - r));
}

// Threefry-2x32-20, matching jax._src.prng.threefry2x32 exactly.
__device__ __forceinline__ void threefry2x32(unsigned k0, unsigned k1,
                                             unsigned c0, unsigned c1,
                                             unsigned& o0, unsigned& o1) {
    unsigned ks2 = k0 ^ k1 ^ 0x1BD11BDAu;
    unsigned x0 = c0 + k0, x1 = c1 + k1;
#define TF_R(rot) { x0 += x1; x1 = rotl32(x1, rot); x1 ^= x0; }
    TF_R(13) TF_R(15) TF_R(26) TF_R(6)
    x0 += k1;  x1 += ks2 + 1u;
    TF_R(17) TF_R(29) TF_R(16) TF_R(24)
    x0 += ks2; x1 += k0 + 2u;
    TF_R(13) TF_R(15) TF_R(26) TF_R(6)
    x0 += k0;  x1 += k1 + 3u;
    TF_R(17) TF_R(29) TF_R(16) TF_R(24)
    x0 += k1;  x1 += ks2 + 4u;
    TF_R(13) TF_R(15) TF_R(26) TF_R(6)
    x0 += ks2; x1 += k0 + 5u;
#undef TF_R
    o0 = x0; o1 = x1;
}

// XLA's f32 ErfInv expansion (Giles polynomial).
__device__ __forceinline__ float erfinv_xla(float x) {
    float w = -log1pf(-x * x);
    float p;
    if (w < 5.0f) {
        w = w - 2.5f;
        p = 2.81022636e-08f;
        p = fmaf(p, w, 3.43273939e-07f);
        p = fmaf(p, w, -3.5233877e-06f);
        p = fmaf(p, w, -4.39150654e-06f);
        p = fmaf(p, w, 0.00021858087f);
        p = fmaf(p, w, -0.00125372503f);
        p = fmaf(p, w, -0.00417768164f);
        p = fmaf(p, w, 0.246640727f);
        p = fmaf(p, w, 1.50140941f);
    } else {
        w = sqrtf(w) - 3.0f;
        p = -0.000200214257f;
        p = fmaf(p, w, 0.000100950558f);
        p = fmaf(p, w, 0.00134934322f);
        p = fmaf(p, w, -0.00367342844f);
        p = fmaf(p, w, 0.00573950773f);
        p = fmaf(p, w, -0.0076224613f);
        p = fmaf(p, w, 0.00943887047f);
        p = fmaf(p, w, 1.00167406f);
        p = fmaf(p, w, 2.83297682f);
    }
    return p * x;
}

// LDS byte offset with XOR swizzle on a [64][512] f16 tile.
__device__ __forceinline__ unsigned lds_off(int row, int colByte) {
    return (unsigned)(row * 1024 + (colByte ^ ((row & 7) << 4)));
}

// One hidden layer, operand-swapped (D = W^T * X^T), in-place on `act`.
// Wave wv owns output cols n = wv*64..+63 for ALL 64 batch rows.
template <int NKC>
__device__ __forceinline__ void layer_swapped(f16* act, const f16* __restrict__ Wp,
                                              const float* bias_l,
                                              int wv, int lk, int lc) {
    f32x4 acc[4][4];
#pragma unroll
    for (int tn = 0; tn < 4; ++tn) {
        // bias folded into acc init; broadcast LDS read (same addr across 16 lanes)
        f32x4 bv = *(const f32x4*)(bias_l + wv * 64 + tn * 16 + lk * 4);
#pragma unroll
        for (int tb = 0; tb < 4; ++tb) acc[tn][tb] = bv;
    }

#pragma unroll 2
    for (int kc = 0; kc < NKC; ++kc) {
        f16x8 wfr[4];
#pragma unroll
        for (int tn = 0; tn < 4; ++tn)
            wfr[tn] = *(const f16x8*)(Wp + ((size_t)(kc * 4 + lk) * HID + wv * 64 + tn * 16 + lc) * 8);
        f16x8 afr[4];
#pragma unroll
        for (int tb = 0; tb < 4; ++tb)
            afr[tb] = *(const f16x8*)((const char*)act + lds_off(tb * 16 + lc, kc * 64 + lk * 16));
#pragma unroll
        for (int tn = 0; tn < 4; ++tn)
#pragma unroll
            for (int tb = 0; tb < 4; ++tb)
                acc[tn][tb] = __builtin_amdgcn_mfma_f32_16x16x32_f16(wfr[tn], afr[tb], acc[tn][tb], 0, 0, 0);
    }
    __syncthreads();  // all reads of act complete -> safe to overwrite
    // D frag: col=lane&15 -> batch row; row=(lane>>4)*4+r -> 4 CONSECUTIVE hidden cols.
#pragma unroll
    for (int tn = 0; tn < 4; ++tn)
#pragma unroll
        for (int tb = 0; tb < 4; ++tb) {
            f16x4 v;
#pragma unroll
            for (int r = 0; r < 4; ++r) v[r] = (f16)fmaxf(acc[tn][tb][r], 0.0f);
            int brow = tb * 16 + lc;
            int nb = (wv * 64 + tn * 16 + lk * 4) * 2;
            *(f16x4*)((char*)act + lds_off(brow, nb)) = v;  // ds_write_b64
        }
    __syncthreads();
}

__global__ __launch_bounds__(512, 4) void didi_main(
    const float* __restrict__ x1g,
    const float* __restrict__ b0g, const float* __restrict__ b1g,
    const float* __restrict__ b2g, const float* __restrict__ b3g,
    const float* __restrict__ b4g,
    const f16* __restrict__ wsp,
    float* __restrict__ outg) {
    __shared__ __align__(16) f16 act[BM * HID];        // 64 KB, in-place ping
    __shared__ __align__(16) float bias_lds[4 * HID];  // 8 KB

    const f16* W0p = wsp + OFF_W0;
    const f16* W1p = wsp + OFF_W1;
    const f16* W2p = wsp + OFF_W2;
    const f16* W3p = wsp + OFF_W3;
    const f16* W4p = wsp + OFF_W4;

    const int tid = threadIdx.x;
    const int wv = tid >> 6;   // wave 0..7
    const int ln = tid & 63;
    const int lk = ln >> 4;    // 0..3
    const int lc = ln & 15;    // 0..15
    const int rowBase = blockIdx.x * BM;

    // Stage biases L0-L3 into LDS (f32).
    for (int o = tid; o < HID; o += 512) {
        bias_lds[o] = b0g[o];
        bias_lds[HID + o] = b1g[o];
        bias_lds[2 * HID + o] = b2g[o];
        bias_lds[3 * HID + o] = b3g[o];
    }
    // L4 bias fragment: lane's 4 dims = lk*4+r.
    f32x4 bias4v = *(const f32x4*)(b4g + lk * 4);

    // Zero act once (uninitialized LDS may hold NaN patterns; padded W0 rows need 0*finite).
    {
        f16x8 z = {};
        for (int o = tid; o < (BM * HID) / 8; o += 512)
            *(f16x8*)(act + o * 8) = z;
    }
    __syncthreads();

    // x-state: wave wv (0..3) lane (lk,lc) holds rows wv*16+lc, dims lk*4..+3 (dim-contiguous!)
    f32x4 xr = {}, x1r = {};
    if (wv < 4) {
        int grow = rowBase + wv * 16 + lc;
        x1r = *(const f32x4*)(x1g + grow * DIMS_X + lk * 4);
        xr = x1r;
        int lrow = wv * 16 + lc;
        f16x4 xf, x1f;
#pragma unroll
        for (int r = 0; r < 4; ++r) { xf[r] = (f16)xr[r]; x1f[r] = (f16)x1r[r]; }
        *(f16x4*)((char*)act + lds_off(lrow, lk * 8)) = xf;        // x_t cols 0-15
        *(f16x4*)((char*)act + lds_off(lrow, 32 + lk * 8)) = x1f;  // x_1 cols 16-31
        if (lk == 0)
            *(f16*)((char*)act + lds_off(lrow, 64)) = (f16)1.0f;   // t col 32
    }
    __syncthreads();

    const float dstep = -1.0f / 127.0f;

#pragma unroll 1
    for (int i = 0; i < NSTEPS; ++i) {
        layer_swapped<2>(act, W0p, bias_lds, wv, lk, lc);
        layer_swapped<16>(act, W1p, bias_lds + HID, wv, lk, lc);
        layer_swapped<16>(act, W2p, bias_lds + 2 * HID, wv, lk, lc);
        layer_swapped<16>(act, W3p, bias_lds + 3 * HID, wv, lk, lc);

        float t  = 1.0f + (float)i * dstep;
        float tp = (i == NSTEPS - 1) ? 0.0f : 1.0f + (float)(i + 1) * dstep;

        if (wv < 4) {
            // L4 swapped: D[n=16][brow=16] per wave; wave reads ONLY its own 16 rows.
            f32x4 acc4 = bias4v;
#pragma unroll 4
            for (int kc = 0; kc < 16; ++kc) {
                f16x8 w4fr = *(const f16x8*)(W4p + ((size_t)(kc * 4 + lk) * 16 + lc) * 8);
                f16x8 afr = *(const f16x8*)((const char*)act + lds_off(wv * 16 + lc, kc * 64 + lk * 16));
                acc4 = __builtin_amdgcn_mfma_f32_16x16x32_f16(w4fr, afr, acc4, 0, 0, 0);
            }
            float ca = (t - tp) / t;
            float cb = tp / t;
            float sig = sqrtf(((0.01f * tp) * (t - tp)) / t);
            unsigned fk0, fk1;
            threefry2x32(0u, 42u, 0u, (unsigned)i, fk0, fk1);  // fold_in(key(42), i)
            int grow = rowBase + wv * 16 + lc;
            int lrow = wv * 16 + lc;
            f16x4 xf, x1f;
#pragma unroll
            for (int r = 0; r < 4; ++r) {
                float drift = acc4[r];  // bias pre-added
                unsigned flat = (unsigned)grow * 16u + (unsigned)(lk * 4 + r);
                // jax_threefry_partitionable: counter = (0, flat); draw = o0 ^ o1.
                unsigned o0, o1;
                threefry2x32(fk0, fk1, 0u, flat, o0, o1);
                unsigned bits = o0 ^ o1;
                float u01 = __uint_as_float((bits >> 9) | 0x3f800000u) - 1.0f;
                float u = u01 * 2.0f + (-0.99999994f);
                u = fmaxf(-0.99999994f, u);
                float nz = 1.4142135623730951f * erfinv_xla(u);
                float x = xr[r];
                float pred = x - t * drift;
                float xn = ca * pred + cb * x;
                xn = xn + sig * nz;
                xr[r] = xn;
                xf[r] = (f16)xn;
                x1f[r] = (f16)x1r[r];
            }
            // Re-stage next input over cols 0-32 (own rows only; per-wave DS order makes
            // this safe w.r.t. this wave's L4 reads). Cols 33-63 hold finite h3 garbage
            // which meets exact-zero padded W0 rows -> contributes 0.
            *(f16x4*)((char*)act + lds_off(lrow, lk * 8)) = xf;
            *(f16x4*)((char*)act + lds_off(lrow, 32 + lk * 8)) = x1f;
            if (lk == 0)
                *(f16*)((char*)act + lds_off(lrow, 64)) = (f16)tp;
        }
        __syncthreads();
    }

    if (wv < 4) {
        int grow = rowBase + wv * 16 + lc;
        *(f32x4*)(outg + grow * DIMS_X + lk * 4) = xr;
    }
}

extern "C" void kernel_launch(void* const* d_in, const int* in_sizes, int n_in,
                              void* d_out, int out_size, void* d_ws, size_t ws_size,
                              hipStream_t stream) {
    const float* x1 = (const float*)d_in[0];
    const float* w0 = (const float*)d_in[1];
    const float* b0 = (const float*)d_in[2];
    const float* w1 = (const float*)d_in[3];
    const float* b1 = (const float*)d_in[4];
    const float* w2 = (const float*)d_in[5];
    const float* b2 = (const float*)d_in[6];
    const float* w3 = (const float*)d_in[7];
    const float* b3 = (const float*)d_in[8];
    const float* w4 = (const float*)d_in[9];
    const float* b4 = (const float*)d_in[10];
    f16* ws = (f16*)d_ws;

    hipLaunchKernelGGL(pack_w0_kernel, dim3(128), dim3(256), 0, stream, w0, ws + OFF_W0);
    hipLaunchKernelGGL(pack_w_kernel, dim3(1024), dim3(256), 0, stream, w1, ws + OFF_W1, 512, 512, 512);
    hipLaunchKernelGGL(pack_w_kernel, dim3(1024), dim3(256), 0, stream, w2, ws + OFF_W2, 512, 512, 512);
    hipLaunchKernelGGL(pack_w_kernel, dim3(1024), dim3(256), 0, stream, w3, ws + OFF_W3, 512, 512, 512);
    hipLaunchKernelGGL(pack_w_kernel, dim3(32), dim3(256), 0, stream, w4, ws + OFF_W4, 512, 512, 16);

    hipLaunchKernelGGL(didi_main, dim3(BATCH / BM), dim3(512), 0, stream,
                       x1, b0, b1, b2, b3, b4, (const f16*)ws, (float*)d_out);
}

// Round 4
// 5691.689 us; speedup vs baseline: 2.0403x; 1.5804x over previous
//
#include <hip/hip_runtime.h>

typedef _Float16 f16;
typedef __attribute__((ext_vector_type(4))) _Float16 f16x4;
typedef __attribute__((ext_vector_type(8))) _Float16 f16x8;
typedef __attribute__((ext_vector_type(4))) float f32x4;

#define HID 512
#define DIMS_X 16
#define NSTEPS 127
#define BM 128
#define BATCH 32768

// ws f16 layout offsets (elements)
#define OFF_W0 0
#define OFF_W1 32768
#define OFF_W2 (32768 + 262144)
#define OFF_W3 (32768 + 2 * 262144)
#define OFF_W4 (32768 + 3 * 262144)

// Pack f32 row-major [K][N] weights into f16 fragment-linear [Kpad/8][N][8].
__global__ void pack_w_kernel(const float* __restrict__ w, f16* __restrict__ out,
                              int K, int Kpad, int N) {
    int idx = blockIdx.x * blockDim.x + threadIdx.x;
    if (idx >= Kpad * N) return;
    int k = idx / N, n = idx - k * N;
    float v = (k < K) ? w[k * N + n] : 0.0f;
    out[(((k >> 3) * N) + n) * 8 + (k & 7)] = (f16)v;
}

// W0 pack with input-row permutation to the kernel's input layout:
// new rows 0-15 = x_t (orig rows 1..16), 16-31 = x_1 (orig 17..32), 32 = t (orig 0), 33-63 = 0.
__global__ void pack_w0_kernel(const float* __restrict__ w, f16* __restrict__ out) {
    int idx = blockIdx.x * blockDim.x + threadIdx.x;
    if (idx >= 64 * HID) return;
    int kn = idx / HID, n = idx - kn * HID;
    float v;
    if (kn < 32) v = w[(kn + 1) * HID + n];
    else if (kn == 32) v = w[n];
    else v = 0.0f;
    out[(((kn >> 3) * HID) + n) * 8 + (kn & 7)] = (f16)v;
}

__device__ __forceinline__ unsigned rotl32(unsigned x, int r) {
    return (x << r) | (x >> (32 - r));
}

// Threefry-2x32-20, matching jax._src.prng.threefry2x32 exactly.
__device__ __forceinline__ void threefry2x32(unsigned k0, unsigned k1,
                                             unsigned c0, unsigned c1,
                                             unsigned& o0, unsigned& o1) {
    unsigned ks2 = k0 ^ k1 ^ 0x1BD11BDAu;
    unsigned x0 = c0 + k0, x1 = c1 + k1;
#define TF_R(rot) { x0 += x1; x1 = rotl32(x1, rot); x1 ^= x0; }
    TF_R(13) TF_R(15) TF_R(26) TF_R(6)
    x0 += k1;  x1 += ks2 + 1u;
    TF_R(17) TF_R(29) TF_R(16) TF_R(24)
    x0 += ks2; x1 += k0 + 2u;
    TF_R(13) TF_R(15) TF_R(26) TF_R(6)
    x0 += k0;  x1 += k1 + 3u;
    TF_R(17) TF_R(29) TF_R(16) TF_R(24)
    x0 += k1;  x1 += ks2 + 4u;
    TF_R(13) TF_R(15) TF_R(26) TF_R(6)
    x0 += ks2; x1 += k0 + 5u;
#undef TF_R
    o0 = x0; o1 = x1;
}

// XLA's f32 ErfInv expansion (Giles polynomial).
__device__ __forceinline__ float erfinv_xla(float x) {
    float w = -log1pf(-x * x);
    float p;
    if (w < 5.0f) {
        w = w - 2.5f;
        p = 2.81022636e-08f;
        p = fmaf(p, w, 3.43273939e-07f);
        p = fmaf(p, w, -3.5233877e-06f);
        p = fmaf(p, w, -4.39150654e-06f);
        p = fmaf(p, w, 0.00021858087f);
        p = fmaf(p, w, -0.00125372503f);
        p = fmaf(p, w, -0.00417768164f);
        p = fmaf(p, w, 0.246640727f);
        p = fmaf(p, w, 1.50140941f);
    } else {
        w = sqrtf(w) - 3.0f;
        p = -0.000200214257f;
        p = fmaf(p, w, 0.000100950558f);
        p = fmaf(p, w, 0.00134934322f);
        p = fmaf(p, w, -0.00367342844f);
        p = fmaf(p, w, 0.00573950773f);
        p = fmaf(p, w, -0.0076224613f);
        p = fmaf(p, w, 0.00943887047f);
        p = fmaf(p, w, 1.00167406f);
        p = fmaf(p, w, 2.83297682f);
    }
    return p * x;
}

// LDS byte offset with XOR swizzle on a [BM][512] f16 tile.
__device__ __forceinline__ unsigned lds_off(int row, int colByte) {
    return (unsigned)(row * 1024 + (colByte ^ ((row & 7) << 4)));
}

// One kc sub-step: MFMA 4x8 tiles with `wc` (current W frags), prefetch kc+1's
// W frags into `wn`. Named cur/nxt sets (no runtime indexing -> stays in regs).
#define KC_BODY(kc, wc, wn, NKC)                                                      \
    {                                                                                 \
        if ((kc) + 1 < (NKC)) {                                                       \
            const f16* wk = wbase + (size_t)((kc) + 1) * (4 * HID * 8);               \
            wn[0] = *(const f16x8*)(wk);                                              \
            wn[1] = *(const f16x8*)(wk + 128);                                        \
            wn[2] = *(const f16x8*)(wk + 256);                                        \
            wn[3] = *(const f16x8*)(wk + 384);                                        \
        }                                                                             \
        f16x8 afr[8];                                                                 \
        _Pragma("unroll")                                                             \
        for (int tb = 0; tb < 8; ++tb)                                                \
            afr[tb] = *(const f16x8*)((const char*)act +                              \
                                      lds_off(tb * 16 + lc, (kc) * 64 + lk * 16));    \
        _Pragma("unroll")                                                             \
        for (int tn = 0; tn < 4; ++tn)                                                \
            _Pragma("unroll")                                                         \
            for (int tb = 0; tb < 8; ++tb)                                            \
                acc[tn][tb] = __builtin_amdgcn_mfma_f32_16x16x32_f16(                 \
                    wc[tn], afr[tb], acc[tn][tb], 0, 0, 0);                           \
    }

// One hidden layer, operand-swapped (D = W^T * X^T), in-place on `act`.
// Wave wv owns output cols n = wv*64..+63 for ALL 128 batch rows.
template <int NKC>
__device__ __forceinline__ void layer_swapped(f16* act, const f16* __restrict__ Wp,
                                              const float* bias_l,
                                              int wv, int lk, int lc) {
    f32x4 acc[4][8];
#pragma unroll
    for (int tn = 0; tn < 4; ++tn) {
        f32x4 bv = *(const f32x4*)(bias_l + wv * 64 + tn * 16 + lk * 4);
#pragma unroll
        for (int tb = 0; tb < 8; ++tb) acc[tn][tb] = bv;
    }

    const f16* wbase = Wp + ((size_t)lk * HID + wv * 64 + lc) * 8;
    f16x8 wA[4], wB[4];
    wA[0] = *(const f16x8*)(wbase);
    wA[1] = *(const f16x8*)(wbase + 128);
    wA[2] = *(const f16x8*)(wbase + 256);
    wA[3] = *(const f16x8*)(wbase + 384);

#pragma unroll 1
    for (int kp = 0; kp < NKC / 2; ++kp) {
        KC_BODY(2 * kp, wA, wB, NKC)
        KC_BODY(2 * kp + 1, wB, wA, NKC)
    }

    __syncthreads();  // all reads of act complete -> safe to overwrite
    // D frag: col=lane&15 -> batch row; row=(lane>>4)*4+r -> 4 CONSECUTIVE hidden cols.
#pragma unroll
    for (int tn = 0; tn < 4; ++tn)
#pragma unroll
        for (int tb = 0; tb < 8; ++tb) {
            f16x4 v;
#pragma unroll
            for (int r = 0; r < 4; ++r) v[r] = (f16)fmaxf(acc[tn][tb][r], 0.0f);
            int brow = tb * 16 + lc;
            int nb = (wv * 64 + tn * 16 + lk * 4) * 2;
            *(f16x4*)((char*)act + lds_off(brow, nb)) = v;  // ds_write_b64
        }
    __syncthreads();
}

__global__ __launch_bounds__(512, 2) void didi_main(
    const float* __restrict__ x1g,
    const float* __restrict__ b0g, const float* __restrict__ b1g,
    const float* __restrict__ b2g, const float* __restrict__ b3g,
    const float* __restrict__ b4g,
    const f16* __restrict__ wsp,
    float* __restrict__ outg) {
    __shared__ __align__(16) f16 act[BM * HID];        // 128 KB, in-place
    __shared__ __align__(16) float bias_lds[4 * HID];  // 8 KB

    const f16* W0p = wsp + OFF_W0;
    const f16* W1p = wsp + OFF_W1;
    const f16* W2p = wsp + OFF_W2;
    const f16* W3p = wsp + OFF_W3;
    const f16* W4p = wsp + OFF_W4;

    const int tid = threadIdx.x;
    const int wv = tid >> 6;   // wave 0..7
    const int ln = tid & 63;
    const int lk = ln >> 4;    // 0..3
    const int lc = ln & 15;    // 0..15
    const int rowBase = blockIdx.x * BM;

    // Stage biases L0-L3 into LDS (f32).
    for (int o = tid; o < HID; o += 512) {
        bias_lds[o] = b0g[o];
        bias_lds[HID + o] = b1g[o];
        bias_lds[2 * HID + o] = b2g[o];
        bias_lds[3 * HID + o] = b3g[o];
    }
    // L4 bias fragment: lane's 4 dims = lk*4+r.
    f32x4 bias4v = *(const f32x4*)(b4g + lk * 4);

    // Zero act once (padded W0 rows need 0 * finite).
    {
        f16x8 z = {};
        for (int o = tid; o < (BM * HID) / 8; o += 512)
            *(f16x8*)(act + o * 8) = z;
    }
    __syncthreads();

    // x-state: wave wv lane (lk,lc) holds row wv*16+lc, dims lk*4..+3 (dim-contiguous).
    f32x4 xr, x1r;
    {
        int grow = rowBase + wv * 16 + lc;
        x1r = *(const f32x4*)(x1g + grow * DIMS_X + lk * 4);
        xr = x1r;
        int lrow = wv * 16 + lc;
        f16x4 xf, x1f;
#pragma unroll
        for (int r = 0; r < 4; ++r) { xf[r] = (f16)xr[r]; x1f[r] = (f16)x1r[r]; }
        *(f16x4*)((char*)act + lds_off(lrow, lk * 8)) = xf;        // x_t cols 0-15
        *(f16x4*)((char*)act + lds_off(lrow, 32 + lk * 8)) = x1f;  // x_1 cols 16-31
        if (lk == 0)
            *(f16*)((char*)act + lds_off(lrow, 64)) = (f16)1.0f;   // t col 32
    }
    __syncthreads();

    const float dstep = -1.0f / 127.0f;

#pragma unroll 1
    for (int i = 0; i < NSTEPS; ++i) {
        layer_swapped<2>(act, W0p, bias_lds, wv, lk, lc);
        layer_swapped<16>(act, W1p, bias_lds + HID, wv, lk, lc);
        layer_swapped<16>(act, W2p, bias_lds + 2 * HID, wv, lk, lc);
        layer_swapped<16>(act, W3p, bias_lds + 3 * HID, wv, lk, lc);

        float t  = 1.0f + (float)i * dstep;
        float tp = (i == NSTEPS - 1) ? 0.0f : 1.0f + (float)(i + 1) * dstep;

        {
            // L4 swapped: each wave computes 16 dims x its own 16 rows, K=512.
            f32x4 acc4 = bias4v;
#pragma unroll 4
            for (int kc = 0; kc < 16; ++kc) {
                f16x8 w4fr = *(const f16x8*)(W4p + ((size_t)(kc * 4 + lk) * 16 + lc) * 8);
                f16x8 afr = *(const f16x8*)((const char*)act + lds_off(wv * 16 + lc, kc * 64 + lk * 16));
                acc4 = __builtin_amdgcn_mfma_f32_16x16x32_f16(w4fr, afr, acc4, 0, 0, 0);
            }
            float ca = (t - tp) / t;
            float cb = tp / t;
            float sig = sqrtf(((0.01f * tp) * (t - tp)) / t);
            unsigned fk0, fk1;
            threefry2x32(0u, 42u, 0u, (unsigned)i, fk0, fk1);  // fold_in(key(42), i)
            int grow = rowBase + wv * 16 + lc;
            int lrow = wv * 16 + lc;
            f16x4 xf, x1f;
#pragma unroll
            for (int r = 0; r < 4; ++r) {
                float drift = acc4[r];  // bias pre-added
                unsigned flat = (unsigned)grow * 16u + (unsigned)(lk * 4 + r);
                // jax_threefry_partitionable: counter = (0, flat); draw = o0 ^ o1.
                unsigned o0, o1;
                threefry2x32(fk0, fk1, 0u, flat, o0, o1);
                unsigned bits = o0 ^ o1;
                float u01 = __uint_as_float((bits >> 9) | 0x3f800000u) - 1.0f;
                float u = u01 * 2.0f + (-0.99999994f);
                u = fmaxf(-0.99999994f, u);
                float nz = 1.4142135623730951f * erfinv_xla(u);
                float x = xr[r];
                float pred = x - t * drift;
                float xn = ca * pred + cb * x;
                xn = xn + sig * nz;
                xr[r] = xn;
                xf[r] = (f16)xn;
                x1f[r] = (f16)x1r[r];
            }
            // Re-stage next input over cols 0-32 (own rows only; per-wave DS order makes
            // this safe w.r.t. this wave's L4 reads). Cols 33-63 hold finite h3 garbage
            // which meets exact-zero padded W0 rows -> contributes 0.
            *(f16x4*)((char*)act + lds_off(lrow, lk * 8)) = xf;
            *(f16x4*)((char*)act + lds_off(lrow, 32 + lk * 8)) = x1f;
            if (lk == 0)
                *(f16*)((char*)act + lds_off(lrow, 64)) = (f16)tp;
        }
        __syncthreads();
    }

    {
        int grow = rowBase + wv * 16 + lc;
        *(f32x4*)(outg + grow * DIMS_X + lk * 4) = xr;
    }
}

extern "C" void kernel_launch(void* const* d_in, const int* in_sizes, int n_in,
                              void* d_out, int out_size, void* d_ws, size_t ws_size,
                              hipStream_t stream) {
    const float* x1 = (const float*)d_in[0];
    const float* w0 = (const float*)d_in[1];
    const float* b0 = (const float*)d_in[2];
    const float* w1 = (const float*)d_in[3];
    const float* b1 = (const float*)d_in[4];
    const float* w2 = (const float*)d_in[5];
    const float* b2 = (const float*)d_in[6];
    const float* w3 = (const float*)d_in[7];
    const float* b3 = (const float*)d_in[8];
    const float* w4 = (const float*)d_in[9];
    const float* b4 = (const float*)d_in[10];
    f16* ws = (f16*)d_ws;

    hipLaunchKernelGGL(pack_w0_kernel, dim3(128), dim3(256), 0, stream, w0, ws + OFF_W0);
    hipLaunchKernelGGL(pack_w_kernel, dim3(1024), dim3(256), 0, stream, w1, ws + OFF_W1, 512, 512, 512);
    hipLaunchKernelGGL(pack_w_kernel, dim3(1024), dim3(256), 0, stream, w2, ws + OFF_W2, 512, 512, 512);
    hipLaunchKernelGGL(pack_w_kernel, dim3(1024), dim3(256), 0, stream, w3, ws + OFF_W3, 512, 512, 512);
    hipLaunchKernelGGL(pack_w_kernel, dim3(32), dim3(256), 0, stream, w4, ws + OFF_W4, 512, 512, 16);

    hipLaunchKernelGGL(didi_main, dim3(BATCH / BM), dim3(512), 0, stream,
                       x1, b0, b1, b2, b3, b4, (const f16*)ws, (float*)d_out);
}